// Round 9
// baseline (289.003 us; speedup 1.0000x reference)
//
#include <hip/hip_runtime.h>

#define S_LEN 16
#define NMODEL 4096
#define DHEAD 128
#define HHEADS 32
#define MCACHE 8192
#define SPLITK 16
#define KSLICE (NMODEL / SPLITK)   // 256
#define CHUNK 128
#define NCHUNK (MCACHE / CHUNK)    // 64
#define M_PAD 132                  // sct row stride: 528 B, 16B-aligned

#define PART_ELEMS  ((size_t)3 * SPLITK * S_LEN * NMODEL)                  // 3.15M
#define OPART_ELEMS ((size_t)HHEADS * NCHUNK * S_LEN * DHEAD)              // 4.19M
#define REGION_ELEMS (PART_ELEMS > OPART_ELEMS ? PART_ELEMS : OPART_ELEMS)

// ---------------- Kernel 1: split-K partial QKV projection ----------------
__global__ __launch_bounds__(256) void qkv_gemm(const float* __restrict__ X,
                                                const float* __restrict__ Wq,
                                                const float* __restrict__ Wk,
                                                const float* __restrict__ Wv,
                                                float* __restrict__ part) {
    const int tid   = threadIdx.x;
    const int col2  = blockIdx.x * 256 + tid;
    const int split = blockIdx.y;
    const int mat   = blockIdx.z;
    const float* __restrict__ W = (mat == 0) ? Wq : (mat == 1) ? Wk : Wv;
    const int k0 = split * KSLICE;

    __shared__ float Xs[KSLICE][S_LEN];     // 16 KB
    for (int i = tid; i < KSLICE * S_LEN; i += 256) {
        const int s = i & 15, k = i >> 4;
        Xs[k][s] = X[s * NMODEL + k0 + k];
    }
    __syncthreads();

    float2 acc[S_LEN];
#pragma unroll
    for (int s = 0; s < S_LEN; ++s) { acc[s].x = 0.f; acc[s].y = 0.f; }

    const float2* __restrict__ Wp = (const float2*)(W + (size_t)k0 * NMODEL) + col2;

#pragma unroll 8
    for (int k = 0; k < KSLICE; ++k) {
        const float2 w = Wp[(size_t)k * (NMODEL / 2)];
        const float4* __restrict__ xr = (const float4*)&Xs[k][0];
#pragma unroll
        for (int s4 = 0; s4 < 4; ++s4) {
            const float4 xv = xr[s4];
            acc[s4 * 4 + 0].x += xv.x * w.x;  acc[s4 * 4 + 0].y += xv.x * w.y;
            acc[s4 * 4 + 1].x += xv.y * w.x;  acc[s4 * 4 + 1].y += xv.y * w.y;
            acc[s4 * 4 + 2].x += xv.z * w.x;  acc[s4 * 4 + 2].y += xv.z * w.y;
            acc[s4 * 4 + 3].x += xv.w * w.x;  acc[s4 * 4 + 3].y += xv.w * w.y;
        }
    }

    float2* __restrict__ pp =
        (float2*)(part + (size_t)(mat * SPLITK + split) * S_LEN * NMODEL) + col2;
#pragma unroll
    for (int s = 0; s < S_LEN; ++s) pp[(size_t)s * (NMODEL / 2)] = acc[s];
}

// ---------------- Kernel 2: reduce split-K partials ----------------
__global__ __launch_bounds__(256) void qkv_reduce(const float* __restrict__ part,
                                                  float* __restrict__ qkv) {
    const int i4   = blockIdx.x * 256 + threadIdx.x;
    const int flat = i4 * 4;
    const int mat  = flat / (S_LEN * NMODEL);
    const int rem  = flat % (S_LEN * NMODEL);
    float4 sum = {0.f, 0.f, 0.f, 0.f};
#pragma unroll
    for (int sp = 0; sp < SPLITK; ++sp) {
        const float4 v = *(const float4*)(part +
            (size_t)(mat * SPLITK + sp) * (S_LEN * NMODEL) + rem);
        sum.x += v.x; sum.y += v.y; sum.z += v.z; sum.w += v.w;
    }
    *(float4*)(qkv + flat) = sum;
}

// ---------------- Kernel 3: flash-decode partial attention ----------------
// grid = (NCHUNK=64, HHEADS=32), block 256 (4 waves). Wave wv owns
// s = wv*4 + (lane>>4); lane's dslice (lane&15) covers 8 dims; q in regs.
// Main loops: UNBRANCHED affine reads of cacheK/V (stale rows OK);
// block-uniform fixup applies the virtual cache-update at P afterwards.
__global__ __launch_bounds__(256) void attn_partial(const float* __restrict__ qkv,
                                                    const float* __restrict__ cacheK,
                                                    const float* __restrict__ cacheV,
                                                    const int* __restrict__ Pp,
                                                    float* __restrict__ opart,
                                                    float* __restrict__ mstat,
                                                    float* __restrict__ lstat) {
    const int c    = blockIdx.x;
    const int h    = blockIdx.y;
    const int tid  = threadIdx.x;
    const int wv   = tid >> 6;
    const int lane = tid & 63;
    const int P    = *Pp;
    const int c0   = c * CHUNK;
    const int lo   = (P > c0) ? P : c0;
    const int hi   = (P + S_LEN < c0 + CHUNK) ? (P + S_LEN) : (c0 + CHUNK);
    const bool overlap = (lo < hi);          // block-uniform

    const float* qb = qkv;
    const float* kb = qkv + S_LEN * NMODEL;
    const float* vb = qkv + 2 * S_LEN * NMODEL;

    __shared__ float sct[S_LEN][M_PAD];      // 8.4 KB, transposed scores
    __shared__ float mloc[S_LEN], lloc[S_LEN];

    // ---- phase 1: scores; 8 rows/iter, 16 loads in flight, no branches ----
    {
        const int s_mine = wv * 4 + (lane >> 4);
        const int dsl    = lane & 15;
        const int doff   = dsl * 8;
        const float4 q0 = *(const float4*)(qb + s_mine * NMODEL + h * DHEAD + doff);
        const float4 q1 = *(const float4*)(qb + s_mine * NMODEL + h * DHEAD + doff + 4);
        const float* kbase = cacheK + ((size_t)h * MCACHE + c0) * DHEAD + doff;

        for (int m = 0; m < CHUNK; m += 8) {
            float4 ka[8], kc[8];
#pragma unroll
            for (int i = 0; i < 8; ++i) {
                ka[i] = *(const float4*)(kbase + (size_t)(m + i) * DHEAD);
                kc[i] = *(const float4*)(kbase + (size_t)(m + i) * DHEAD + 4);
            }
            float pr[8];
#pragma unroll
            for (int i = 0; i < 8; ++i) {
                pr[i] = ka[i].x * q0.x + ka[i].y * q0.y + ka[i].z * q0.z + ka[i].w * q0.w
                      + kc[i].x * q1.x + kc[i].y * q1.y + kc[i].z * q1.z + kc[i].w * q1.w;
            }
#pragma unroll
            for (int i = 0; i < 8; ++i) {
                float v = pr[i];
                v += __shfl_xor(v, 1, 64);
                v += __shfl_xor(v, 2, 64);
                v += __shfl_xor(v, 4, 64);
                v += __shfl_xor(v, 8, 64);
                pr[i] = v;
            }
            if (dsl == 0) {
#pragma unroll
                for (int i = 0; i < 8; ++i) sct[s_mine][m + i] = pr[i];
            }
        }

        // fixup: recompute overlap rows with freshly-projected k
        if (overlap) {
            for (int gm = lo; gm < hi; ++gm) {
                const float* kr = kb + (size_t)(gm - P) * NMODEL + h * DHEAD + doff;
                const float4 k0 = *(const float4*)(kr);
                const float4 k1 = *(const float4*)(kr + 4);
                float v = k0.x * q0.x + k0.y * q0.y + k0.z * q0.z + k0.w * q0.w
                        + k1.x * q1.x + k1.y * q1.y + k1.z * q1.z + k1.w * q1.w;
                v += __shfl_xor(v, 1, 64);
                v += __shfl_xor(v, 2, 64);
                v += __shfl_xor(v, 4, 64);
                v += __shfl_xor(v, 8, 64);
                if (dsl == 0) sct[s_mine][gm - c0] = v;
            }
        }
    }
    __syncthreads();

    // ---- phase 2: per-s max & sumexp over 128 rows (transposed layout) ----
    {
#pragma unroll
        for (int si = 0; si < 4; ++si) {
            const int s = wv * 4 + si;
            const float v0 = sct[s][lane];
            const float v1 = sct[s][lane + 64];
            float mx = fmaxf(v0, v1);
            for (int off = 32; off > 0; off >>= 1) mx = fmaxf(mx, __shfl_xor(mx, off, 64));
            const float e0 = __expf(v0 - mx);
            const float e1 = __expf(v1 - mx);
            sct[s][lane] = e0; sct[s][lane + 64] = e1;
            float sum = e0 + e1;
            for (int off = 32; off > 0; off >>= 1) sum += __shfl_xor(sum, off, 64);
            if (lane == 0) { mloc[s] = mx; lloc[s] = sum; }
        }
    }
    __syncthreads();

    // ---- phase 3: o[s][d] = sum_m p*V ; affine V reads, fixup after ----
    {
        const int s  = tid >> 4;
        const int d0 = (tid & 15) * 8;
        const float* vbase = cacheV + ((size_t)h * MCACHE + c0) * DHEAD + d0;
        float a[8];
#pragma unroll
        for (int j = 0; j < 8; ++j) a[j] = 0.f;

        for (int m = 0; m < CHUNK; m += 4) {
            const float4 p4 = *(const float4*)&sct[s][m];   // broadcast per s-group
            float4 v0[4], v1[4];
#pragma unroll
            for (int i = 0; i < 4; ++i) {
                v0[i] = *(const float4*)(vbase + (size_t)(m + i) * DHEAD);
                v1[i] = *(const float4*)(vbase + (size_t)(m + i) * DHEAD + 4);
            }
#pragma unroll
            for (int i = 0; i < 4; ++i) {
                const float p = (i == 0) ? p4.x : (i == 1) ? p4.y : (i == 2) ? p4.z : p4.w;
                a[0] += p * v0[i].x; a[1] += p * v0[i].y; a[2] += p * v0[i].z; a[3] += p * v0[i].w;
                a[4] += p * v1[i].x; a[5] += p * v1[i].y; a[6] += p * v1[i].z; a[7] += p * v1[i].w;
            }
        }

        // fixup: overlap rows used stale V; add p*(V_new - V_old)
        if (overlap) {
            for (int gm = lo; gm < hi; ++gm) {
                const float p = sct[s][gm - c0];
                const float* vn = vb + (size_t)(gm - P) * NMODEL + h * DHEAD + d0;
                const float* vo = cacheV + ((size_t)h * MCACHE + gm) * DHEAD + d0;
                const float4 n0 = *(const float4*)(vn);
                const float4 n1 = *(const float4*)(vn + 4);
                const float4 o0 = *(const float4*)(vo);
                const float4 o1 = *(const float4*)(vo + 4);
                a[0] += p * (n0.x - o0.x); a[1] += p * (n0.y - o0.y);
                a[2] += p * (n0.z - o0.z); a[3] += p * (n0.w - o0.w);
                a[4] += p * (n1.x - o1.x); a[5] += p * (n1.y - o1.y);
                a[6] += p * (n1.z - o1.z); a[7] += p * (n1.w - o1.w);
            }
        }

        const size_t ob = (((size_t)h * NCHUNK + c) * S_LEN + s) * DHEAD + d0;
        float4 w0; w0.x = a[0]; w0.y = a[1]; w0.z = a[2]; w0.w = a[3];
        float4 w1; w1.x = a[4]; w1.y = a[5]; w1.z = a[6]; w1.w = a[7];
        *(float4*)(opart + ob)     = w0;
        *(float4*)(opart + ob + 4) = w1;
    }
    if (tid < S_LEN) {
        mstat[((size_t)h * NCHUNK + c) * S_LEN + tid] = mloc[tid];
        lstat[((size_t)h * NCHUNK + c) * S_LEN + tid] = lloc[tid];
    }
}

// ---------------- Kernel 4: combine chunk partials ----------------
__global__ __launch_bounds__(128) void attn_combine(const float* __restrict__ opart,
                                                    const float* __restrict__ mstat,
                                                    const float* __restrict__ lstat,
                                                    float* __restrict__ out) {
    const int d = threadIdx.x;
    const int s = blockIdx.x;
    const int h = blockIdx.y;

    float gmax = -1e30f;
#pragma unroll 8
    for (int c = 0; c < NCHUNK; ++c)
        gmax = fmaxf(gmax, mstat[((size_t)h * NCHUNK + c) * S_LEN + s]);

    float L = 0.f, o = 0.f;
#pragma unroll 4
    for (int c = 0; c < NCHUNK; ++c) {
        const size_t si = (size_t)h * NCHUNK * S_LEN + (size_t)c * S_LEN + s;
        const float w = __expf(mstat[si] - gmax);
        L += lstat[si] * w;
        o += w * opart[si * DHEAD + d];
    }
    out[((size_t)h * S_LEN + s) * DHEAD + d] = o / L;
}

extern "C" void kernel_launch(void* const* d_in, const int* in_sizes, int n_in,
                              void* d_out, int out_size, void* d_ws, size_t ws_size,
                              hipStream_t stream) {
    const float* X      = (const float*)d_in[0];
    const float* Wq     = (const float*)d_in[1];
    const float* Wk     = (const float*)d_in[2];
    const float* Wv     = (const float*)d_in[3];
    const float* cacheK = (const float*)d_in[4];
    const float* cacheV = (const float*)d_in[5];
    const int*   P      = (const int*)d_in[6];
    float* out = (float*)d_out;
    float* ws  = (float*)d_ws;

    // ws layout (floats). opart ALIASES part; mstat after max of both regions.
    float* qkv   = ws;                                   // 196608 floats
    float* part  = qkv + 3 * S_LEN * NMODEL;
    float* opart = part;
    float* mstat = part + REGION_ELEMS;
    float* lstat = mstat + (size_t)HHEADS * NCHUNK * S_LEN;

    qkv_gemm<<<dim3(8, SPLITK, 3), 256, 0, stream>>>(X, Wq, Wk, Wv, part);
    qkv_reduce<<<(3 * S_LEN * NMODEL / 4) / 256, 256, 0, stream>>>(part, qkv);
    attn_partial<<<dim3(NCHUNK, HHEADS), 256, 0, stream>>>(qkv, cacheK, cacheV, P,
                                                           opart, mstat, lstat);
    attn_combine<<<dim3(S_LEN, HHEADS), DHEAD, 0, stream>>>(opart, mstat, lstat, out);
}

// Round 10
// 236.283 us; speedup vs baseline: 1.2231x; 1.2231x over previous
//
#include <hip/hip_runtime.h>

#define S_LEN 16
#define NMODEL 4096
#define DHEAD 128
#define HHEADS 32
#define MCACHE 8192
#define SPLITK 16
#define KSLICE (NMODEL / SPLITK)   // 256
#define CHUNK_W 64                 // rows per WAVE (one chunk per wave)
#define NCHT (MCACHE / CHUNK_W)    // 128 chunks per head
#define SPAD 17                    // sct[m][s] row stride (odd -> 2-way max)

#define PART_ELEMS  ((size_t)3 * SPLITK * S_LEN * NMODEL)                  // 3.15M
#define OPART_ELEMS ((size_t)HHEADS * NCHT * S_LEN * DHEAD)               // 8.39M
#define REGION_ELEMS (PART_ELEMS > OPART_ELEMS ? PART_ELEMS : OPART_ELEMS)

// ---------------- Kernel 1: split-K partial QKV projection ----------------
__global__ __launch_bounds__(256) void qkv_gemm(const float* __restrict__ X,
                                                const float* __restrict__ Wq,
                                                const float* __restrict__ Wk,
                                                const float* __restrict__ Wv,
                                                float* __restrict__ part) {
    const int tid   = threadIdx.x;
    const int col2  = blockIdx.x * 256 + tid;
    const int split = blockIdx.y;
    const int mat   = blockIdx.z;
    const float* __restrict__ W = (mat == 0) ? Wq : (mat == 1) ? Wk : Wv;
    const int k0 = split * KSLICE;

    __shared__ float Xs[KSLICE][S_LEN];     // 16 KB
    for (int i = tid; i < KSLICE * S_LEN; i += 256) {
        const int s = i & 15, k = i >> 4;
        Xs[k][s] = X[s * NMODEL + k0 + k];
    }
    __syncthreads();

    float2 acc[S_LEN];
#pragma unroll
    for (int s = 0; s < S_LEN; ++s) { acc[s].x = 0.f; acc[s].y = 0.f; }

    const float2* __restrict__ Wp = (const float2*)(W + (size_t)k0 * NMODEL) + col2;

#pragma unroll 8
    for (int k = 0; k < KSLICE; ++k) {
        const float2 w = Wp[(size_t)k * (NMODEL / 2)];
        const float4* __restrict__ xr = (const float4*)&Xs[k][0];
#pragma unroll
        for (int s4 = 0; s4 < 4; ++s4) {
            const float4 xv = xr[s4];
            acc[s4 * 4 + 0].x += xv.x * w.x;  acc[s4 * 4 + 0].y += xv.x * w.y;
            acc[s4 * 4 + 1].x += xv.y * w.x;  acc[s4 * 4 + 1].y += xv.y * w.y;
            acc[s4 * 4 + 2].x += xv.z * w.x;  acc[s4 * 4 + 2].y += xv.z * w.y;
            acc[s4 * 4 + 3].x += xv.w * w.x;  acc[s4 * 4 + 3].y += xv.w * w.y;
        }
    }

    float2* __restrict__ pp =
        (float2*)(part + (size_t)(mat * SPLITK + split) * S_LEN * NMODEL) + col2;
#pragma unroll
    for (int s = 0; s < S_LEN; ++s) pp[(size_t)s * (NMODEL / 2)] = acc[s];
}

// ---------------- Kernel 2: reduce split-K partials ----------------
__global__ __launch_bounds__(256) void qkv_reduce(const float* __restrict__ part,
                                                  float* __restrict__ qkv) {
    const int i4   = blockIdx.x * 256 + threadIdx.x;
    const int flat = i4 * 4;
    const int mat  = flat / (S_LEN * NMODEL);
    const int rem  = flat % (S_LEN * NMODEL);
    float4 sum = {0.f, 0.f, 0.f, 0.f};
#pragma unroll
    for (int sp = 0; sp < SPLITK; ++sp) {
        const float4 v = *(const float4*)(part +
            (size_t)(mat * SPLITK + sp) * (S_LEN * NMODEL) + rem);
        sum.x += v.x; sum.y += v.y; sum.z += v.z; sum.w += v.w;
    }
    *(float4*)(qkv + flat) = sum;
}

// ---------------- Kernel 3: flash-decode partial attention ----------------
// grid = (NCHT/2 = 64, HHEADS=32), block = 128 (2 independent waves).
// Wave owns its own 64-row chunk for ALL 16 s. Lane = (sq = lane>>4 covering
// s = sq*4..+3, dsl = lane&15 covering dims dsl*8..+7). q in 32 regs.
// K/V rows read ONCE per wave (4-way s-dup merged by coalescer). Branchless
// affine main loops + block-uniform P-fixup.
__global__ __launch_bounds__(128) void attn_partial(const float* __restrict__ qkv,
                                                    const float* __restrict__ cacheK,
                                                    const float* __restrict__ cacheV,
                                                    const int* __restrict__ Pp,
                                                    float* __restrict__ opart,
                                                    float* __restrict__ mstat,
                                                    float* __restrict__ lstat) {
    const int bx   = blockIdx.x;
    const int h    = blockIdx.y;
    const int tid  = threadIdx.x;
    const int wv   = tid >> 6;
    const int lane = tid & 63;
    const int c    = bx * 2 + wv;            // this wave's chunk
    const int c0   = c * CHUNK_W;
    const int P    = *Pp;
    const int lo   = (P > c0) ? P : c0;
    const int hi_  = (P + S_LEN < c0 + CHUNK_W) ? (P + S_LEN) : (c0 + CHUNK_W);
    const bool overlap = (lo < hi_);         // wave-uniform

    const float* qb = qkv;
    const float* kb = qkv + S_LEN * NMODEL;
    const float* vb = qkv + 2 * S_LEN * NMODEL;

    __shared__ float sct[2][CHUNK_W][SPAD];  // 8.7 KB, [m][s] transposed
    __shared__ float ml[2][S_LEN], ll[2][S_LEN];

    const int sq   = lane >> 4;
    const int dsl  = lane & 15;
    const int doff = dsl * 8;

    // ---- phase 1: scores. q regs for 4 s; K row read once per wave ----
    {
        float4 q0[4], q1[4];
#pragma unroll
        for (int j = 0; j < 4; ++j) {
            const int s = sq * 4 + j;
            q0[j] = *(const float4*)(qb + s * NMODEL + h * DHEAD + doff);
            q1[j] = *(const float4*)(qb + s * NMODEL + h * DHEAD + doff + 4);
        }
        const float* kbase = cacheK + ((size_t)h * MCACHE + c0) * DHEAD + doff;

        for (int m = 0; m < CHUNK_W; ++m) {
            const float4 ka = *(const float4*)(kbase + (size_t)m * DHEAD);
            const float4 kc = *(const float4*)(kbase + (size_t)m * DHEAD + 4);
            float pr[4];
#pragma unroll
            for (int j = 0; j < 4; ++j) {
                pr[j] = ka.x * q0[j].x + ka.y * q0[j].y + ka.z * q0[j].z + ka.w * q0[j].w
                      + kc.x * q1[j].x + kc.y * q1[j].y + kc.z * q1[j].z + kc.w * q1[j].w;
            }
#pragma unroll
            for (int j = 0; j < 4; ++j) {
                float v = pr[j];
                v += __shfl_xor(v, 1, 64);
                v += __shfl_xor(v, 2, 64);
                v += __shfl_xor(v, 4, 64);
                v += __shfl_xor(v, 8, 64);
                pr[j] = v;
            }
            if (dsl == 0) {
                float4 w; w.x = pr[0]; w.y = pr[1]; w.z = pr[2]; w.w = pr[3];
                *(float4*)&sct[wv][m][sq * 4] = w;   // 4 lanes, 16B apart: no conflict
            }
        }

        if (overlap) {                        // recompute overlap rows w/ fresh k
            for (int gm = lo; gm < hi_; ++gm) {
                const float* kr = kb + (size_t)(gm - P) * NMODEL + h * DHEAD + doff;
                const float4 ka = *(const float4*)(kr);
                const float4 kc = *(const float4*)(kr + 4);
                float pr[4];
#pragma unroll
                for (int j = 0; j < 4; ++j) {
                    pr[j] = ka.x * q0[j].x + ka.y * q0[j].y + ka.z * q0[j].z + ka.w * q0[j].w
                          + kc.x * q1[j].x + kc.y * q1[j].y + kc.z * q1[j].z + kc.w * q1[j].w;
                }
#pragma unroll
                for (int j = 0; j < 4; ++j) {
                    float v = pr[j];
                    v += __shfl_xor(v, 1, 64);
                    v += __shfl_xor(v, 2, 64);
                    v += __shfl_xor(v, 4, 64);
                    v += __shfl_xor(v, 8, 64);
                    pr[j] = v;
                }
                if (dsl == 0) {
                    float4 w; w.x = pr[0]; w.y = pr[1]; w.z = pr[2]; w.w = pr[3];
                    *(float4*)&sct[wv][gm - c0][sq * 4] = w;
                }
            }
        }
    }
    __syncthreads();

    // ---- phase 2: per-s max & sumexp over this wave's 64 rows ----
    {
        for (int s = 0; s < S_LEN; ++s) {
            const float v = sct[wv][lane][s];        // stride 17 words: <=2-way, free
            float mx = v;
            for (int off = 32; off > 0; off >>= 1) mx = fmaxf(mx, __shfl_xor(mx, off, 64));
            const float e = __expf(v - mx);
            sct[wv][lane][s] = e;
            float sum = e;
            for (int off = 32; off > 0; off >>= 1) sum += __shfl_xor(sum, off, 64);
            if (lane == 0) { ml[wv][s] = mx; ll[wv][s] = sum; }
        }
    }
    __syncthreads();

    // ---- phase 3: o[s][d] partials; V row read once; p4 via b128 broadcast ----
    {
        const float* vbase = cacheV + ((size_t)h * MCACHE + c0) * DHEAD + doff;
        float a[4][8];
#pragma unroll
        for (int j = 0; j < 4; ++j)
#pragma unroll
            for (int k = 0; k < 8; ++k) a[j][k] = 0.f;

        for (int m = 0; m < CHUNK_W; ++m) {
            const float4 p4 = *(const float4*)&sct[wv][m][sq * 4];  // broadcast/16 lanes
            const float4 v0 = *(const float4*)(vbase + (size_t)m * DHEAD);
            const float4 v1 = *(const float4*)(vbase + (size_t)m * DHEAD + 4);
            const float pj[4] = {p4.x, p4.y, p4.z, p4.w};
#pragma unroll
            for (int j = 0; j < 4; ++j) {
                a[j][0] += pj[j] * v0.x; a[j][1] += pj[j] * v0.y;
                a[j][2] += pj[j] * v0.z; a[j][3] += pj[j] * v0.w;
                a[j][4] += pj[j] * v1.x; a[j][5] += pj[j] * v1.y;
                a[j][6] += pj[j] * v1.z; a[j][7] += pj[j] * v1.w;
            }
        }

        if (overlap) {                        // stale-V correction: p*(Vnew-Vold)
            for (int gm = lo; gm < hi_; ++gm) {
                const float4 p4 = *(const float4*)&sct[wv][gm - c0][sq * 4];
                const float* vn = vb + (size_t)(gm - P) * NMODEL + h * DHEAD + doff;
                const float* vo = cacheV + ((size_t)h * MCACHE + gm) * DHEAD + doff;
                const float4 n0 = *(const float4*)(vn);
                const float4 n1 = *(const float4*)(vn + 4);
                const float4 o0 = *(const float4*)(vo);
                const float4 o1 = *(const float4*)(vo + 4);
                const float pj[4] = {p4.x, p4.y, p4.z, p4.w};
#pragma unroll
                for (int j = 0; j < 4; ++j) {
                    a[j][0] += pj[j] * (n0.x - o0.x); a[j][1] += pj[j] * (n0.y - o0.y);
                    a[j][2] += pj[j] * (n0.z - o0.z); a[j][3] += pj[j] * (n0.w - o0.w);
                    a[j][4] += pj[j] * (n1.x - o1.x); a[j][5] += pj[j] * (n1.y - o1.y);
                    a[j][6] += pj[j] * (n1.z - o1.z); a[j][7] += pj[j] * (n1.w - o1.w);
                }
            }
        }

        const size_t ob = (((size_t)h * NCHT + c) * S_LEN) * DHEAD;
#pragma unroll
        for (int j = 0; j < 4; ++j) {
            const int s = sq * 4 + j;
            float4 w0; w0.x = a[j][0]; w0.y = a[j][1]; w0.z = a[j][2]; w0.w = a[j][3];
            float4 w1; w1.x = a[j][4]; w1.y = a[j][5]; w1.z = a[j][6]; w1.w = a[j][7];
            *(float4*)(opart + ob + (size_t)s * DHEAD + doff)     = w0;
            *(float4*)(opart + ob + (size_t)s * DHEAD + doff + 4) = w1;
        }
    }

    // stats (ml/ll valid since the phase2->3 barrier)
    if (tid < 32) {
        const int w2 = tid >> 4, s = tid & 15;
        const int cc = bx * 2 + w2;
        mstat[((size_t)h * NCHT + cc) * S_LEN + s] = ml[w2][s];
        lstat[((size_t)h * NCHT + cc) * S_LEN + s] = ll[w2][s];
    }
}

// ---------------- Kernel 4: combine chunk partials ----------------
__global__ __launch_bounds__(128) void attn_combine(const float* __restrict__ opart,
                                                    const float* __restrict__ mstat,
                                                    const float* __restrict__ lstat,
                                                    float* __restrict__ out) {
    const int d = threadIdx.x;
    const int s = blockIdx.x;
    const int h = blockIdx.y;

    float gmax = -1e30f;
#pragma unroll 8
    for (int c = 0; c < NCHT; ++c)
        gmax = fmaxf(gmax, mstat[((size_t)h * NCHT + c) * S_LEN + s]);

    float L = 0.f, o = 0.f;
#pragma unroll 4
    for (int c = 0; c < NCHT; ++c) {
        const size_t si = (size_t)h * NCHT * S_LEN + (size_t)c * S_LEN + s;
        const float w = __expf(mstat[si] - gmax);
        L += lstat[si] * w;
        o += w * opart[si * DHEAD + d];
    }
    out[((size_t)h * S_LEN + s) * DHEAD + d] = o / L;
}

extern "C" void kernel_launch(void* const* d_in, const int* in_sizes, int n_in,
                              void* d_out, int out_size, void* d_ws, size_t ws_size,
                              hipStream_t stream) {
    const float* X      = (const float*)d_in[0];
    const float* Wq     = (const float*)d_in[1];
    const float* Wk     = (const float*)d_in[2];
    const float* Wv     = (const float*)d_in[3];
    const float* cacheK = (const float*)d_in[4];
    const float* cacheV = (const float*)d_in[5];
    const int*   P      = (const int*)d_in[6];
    float* out = (float*)d_out;
    float* ws  = (float*)d_ws;

    // ws layout (floats). opart ALIASES part; mstat after max of both regions.
    float* qkv   = ws;                                   // 196608 floats
    float* part  = qkv + 3 * S_LEN * NMODEL;
    float* opart = part;
    float* mstat = part + REGION_ELEMS;
    float* lstat = mstat + (size_t)HHEADS * NCHT * S_LEN;

    qkv_gemm<<<dim3(8, SPLITK, 3), 256, 0, stream>>>(X, Wq, Wk, Wv, part);
    qkv_reduce<<<(3 * S_LEN * NMODEL / 4) / 256, 256, 0, stream>>>(part, qkv);
    attn_partial<<<dim3(NCHT / 2, HHEADS), 128, 0, stream>>>(qkv, cacheK, cacheV, P,
                                                             opart, mstat, lstat);
    attn_combine<<<dim3(S_LEN, HHEADS), DHEAD, 0, stream>>>(opart, mstat, lstat, out);
}

// Round 11
// 201.444 us; speedup vs baseline: 1.4347x; 1.1729x over previous
//
#include <hip/hip_runtime.h>

#define S_LEN 16
#define NMODEL 4096
#define DHEAD 128
#define HHEADS 32
#define MCACHE 8192
#define SPLITK 32
#define KSLICE (NMODEL / SPLITK)   // 128
#define CHUNK_W 32                 // rows per WAVE
#define NCHT (MCACHE / CHUNK_W)    // 256 chunks per head
#define SPAD 17

#define PART_ELEMS   ((size_t)3 * SPLITK * S_LEN * NMODEL)        // 6.29M floats
#define OPART_USH    ((size_t)HHEADS * NCHT * S_LEN * DHEAD)      // 16.78M ushorts
#define OPART_FLOATS (OPART_USH / 2)                              // 8.39M floats
#define REGION_ELEMS (PART_ELEMS > OPART_FLOATS ? PART_ELEMS : OPART_FLOATS)
#define STAT_ELEMS   ((size_t)HHEADS * NCHT * S_LEN)              // 131072

__device__ __forceinline__ unsigned short f2bf(float f) {
    unsigned int b = __float_as_uint(f);
    return (unsigned short)((b + 0x7FFFu + ((b >> 16) & 1u)) >> 16);   // RNE
}
__device__ __forceinline__ float bf2f(unsigned short u) {
    return __uint_as_float(((unsigned int)u) << 16);
}

// ---------------- Kernel 1: split-K partial QKV projection ----------------
// grid (8, 32, 3) = 768 blocks (12 waves/CU), block 256.
__global__ __launch_bounds__(256) void qkv_gemm(const float* __restrict__ X,
                                                const float* __restrict__ Wq,
                                                const float* __restrict__ Wk,
                                                const float* __restrict__ Wv,
                                                float* __restrict__ part) {
    const int tid   = threadIdx.x;
    const int col2  = blockIdx.x * 256 + tid;
    const int split = blockIdx.y;
    const int mat   = blockIdx.z;
    const float* __restrict__ W = (mat == 0) ? Wq : (mat == 1) ? Wk : Wv;
    const int k0 = split * KSLICE;

    __shared__ float Xs[KSLICE][S_LEN];     // 8 KB
    for (int i = tid; i < KSLICE * S_LEN; i += 256) {
        const int s = i & 15, k = i >> 4;
        Xs[k][s] = X[s * NMODEL + k0 + k];
    }
    __syncthreads();

    float2 acc[S_LEN];
#pragma unroll
    for (int s = 0; s < S_LEN; ++s) { acc[s].x = 0.f; acc[s].y = 0.f; }

    const float2* __restrict__ Wp = (const float2*)(W + (size_t)k0 * NMODEL) + col2;

#pragma unroll 8
    for (int k = 0; k < KSLICE; ++k) {
        const float2 w = Wp[(size_t)k * (NMODEL / 2)];
        const float4* __restrict__ xr = (const float4*)&Xs[k][0];
#pragma unroll
        for (int s4 = 0; s4 < 4; ++s4) {
            const float4 xv = xr[s4];
            acc[s4 * 4 + 0].x += xv.x * w.x;  acc[s4 * 4 + 0].y += xv.x * w.y;
            acc[s4 * 4 + 1].x += xv.y * w.x;  acc[s4 * 4 + 1].y += xv.y * w.y;
            acc[s4 * 4 + 2].x += xv.z * w.x;  acc[s4 * 4 + 2].y += xv.z * w.y;
            acc[s4 * 4 + 3].x += xv.w * w.x;  acc[s4 * 4 + 3].y += xv.w * w.y;
        }
    }

    float2* __restrict__ pp =
        (float2*)(part + (size_t)(mat * SPLITK + split) * S_LEN * NMODEL) + col2;
#pragma unroll
    for (int s = 0; s < S_LEN; ++s) pp[(size_t)s * (NMODEL / 2)] = acc[s];
}

// ---------------- Kernel 2: reduce split-K partials ----------------
__global__ __launch_bounds__(256) void qkv_reduce(const float* __restrict__ part,
                                                  float* __restrict__ qkv) {
    const int i4   = blockIdx.x * 256 + threadIdx.x;
    const int flat = i4 * 4;
    const int mat  = flat / (S_LEN * NMODEL);
    const int rem  = flat % (S_LEN * NMODEL);
    float4 sum = {0.f, 0.f, 0.f, 0.f};
#pragma unroll 8
    for (int sp = 0; sp < SPLITK; ++sp) {
        const float4 v = *(const float4*)(part +
            (size_t)(mat * SPLITK + sp) * (S_LEN * NMODEL) + rem);
        sum.x += v.x; sum.y += v.y; sum.z += v.z; sum.w += v.w;
    }
    *(float4*)(qkv + flat) = sum;
}

// ---------------- Kernel 3: flash-decode partial attention ----------------
// grid = (NCHT/2 = 128, HHEADS=32) = 4096 blocks (16/CU), block 128 (2 waves).
// Wave owns a 32-row chunk for ALL 16 s; lane = (sq=lane>>4, dsl=lane&15).
// K/V rows read once per wave; branchless affine loops + wave-uniform P-fixup.
__global__ __launch_bounds__(128) void attn_partial(const float* __restrict__ qkv,
                                                    const float* __restrict__ cacheK,
                                                    const float* __restrict__ cacheV,
                                                    const int* __restrict__ Pp,
                                                    unsigned short* __restrict__ opart,
                                                    float* __restrict__ mstat,
                                                    float* __restrict__ lstat) {
    const int bx   = blockIdx.x;
    const int h    = blockIdx.y;
    const int tid  = threadIdx.x;
    const int wv   = tid >> 6;
    const int lane = tid & 63;
    const int c    = bx * 2 + wv;
    const int c0   = c * CHUNK_W;
    const int P    = *Pp;
    const int lo   = (P > c0) ? P : c0;
    const int hi_  = (P + S_LEN < c0 + CHUNK_W) ? (P + S_LEN) : (c0 + CHUNK_W);
    const bool overlap = (lo < hi_);         // wave-uniform

    const float* qb = qkv;
    const float* kb = qkv + S_LEN * NMODEL;
    const float* vb = qkv + 2 * S_LEN * NMODEL;

    __shared__ float sct[2][CHUNK_W][SPAD];  // 4.4 KB
    __shared__ float ml[2][S_LEN], ll[2][S_LEN];

    const int sq   = lane >> 4;
    const int dsl  = lane & 15;
    const int doff = dsl * 8;

    // ---- phase 1: scores ----
    {
        float4 q0[4], q1[4];
#pragma unroll
        for (int j = 0; j < 4; ++j) {
            const int s = sq * 4 + j;
            q0[j] = *(const float4*)(qb + s * NMODEL + h * DHEAD + doff);
            q1[j] = *(const float4*)(qb + s * NMODEL + h * DHEAD + doff + 4);
        }
        const float* kbase = cacheK + ((size_t)h * MCACHE + c0) * DHEAD + doff;

        for (int m = 0; m < CHUNK_W; ++m) {
            const float4 ka = *(const float4*)(kbase + (size_t)m * DHEAD);
            const float4 kc = *(const float4*)(kbase + (size_t)m * DHEAD + 4);
            float pr[4];
#pragma unroll
            for (int j = 0; j < 4; ++j) {
                pr[j] = ka.x * q0[j].x + ka.y * q0[j].y + ka.z * q0[j].z + ka.w * q0[j].w
                      + kc.x * q1[j].x + kc.y * q1[j].y + kc.z * q1[j].z + kc.w * q1[j].w;
            }
#pragma unroll
            for (int j = 0; j < 4; ++j) {
                float v = pr[j];
                v += __shfl_xor(v, 1, 64);
                v += __shfl_xor(v, 2, 64);
                v += __shfl_xor(v, 4, 64);
                v += __shfl_xor(v, 8, 64);
                pr[j] = v;
            }
            if (dsl == 0) {
                float4 w; w.x = pr[0]; w.y = pr[1]; w.z = pr[2]; w.w = pr[3];
                *(float4*)&sct[wv][m][sq * 4] = w;
            }
        }

        if (overlap) {
            for (int gm = lo; gm < hi_; ++gm) {
                const float* kr = kb + (size_t)(gm - P) * NMODEL + h * DHEAD + doff;
                const float4 ka = *(const float4*)(kr);
                const float4 kc = *(const float4*)(kr + 4);
                float pr[4];
#pragma unroll
                for (int j = 0; j < 4; ++j) {
                    pr[j] = ka.x * q0[j].x + ka.y * q0[j].y + ka.z * q0[j].z + ka.w * q0[j].w
                          + kc.x * q1[j].x + kc.y * q1[j].y + kc.z * q1[j].z + kc.w * q1[j].w;
                }
#pragma unroll
                for (int j = 0; j < 4; ++j) {
                    float v = pr[j];
                    v += __shfl_xor(v, 1, 64);
                    v += __shfl_xor(v, 2, 64);
                    v += __shfl_xor(v, 4, 64);
                    v += __shfl_xor(v, 8, 64);
                    pr[j] = v;
                }
                if (dsl == 0) {
                    float4 w; w.x = pr[0]; w.y = pr[1]; w.z = pr[2]; w.w = pr[3];
                    *(float4*)&sct[wv][gm - c0][sq * 4] = w;
                }
            }
        }
    }
    __syncthreads();

    // ---- phase 2: per-s max & sumexp over 32 rows (both 32-lane halves dup) ----
    {
        const int rl = lane & 31;
        for (int s = 0; s < S_LEN; ++s) {
            const float v = sct[wv][rl][s];          // stride 17: conflict-free
            float mx = v;
            for (int off = 16; off > 0; off >>= 1) mx = fmaxf(mx, __shfl_xor(mx, off, 64));
            const float e = __expf(v - mx);
            sct[wv][rl][s] = e;                      // halves write same value: benign
            float sum = e;
            for (int off = 16; off > 0; off >>= 1) sum += __shfl_xor(sum, off, 64);
            if (lane == 0) { ml[wv][s] = mx; ll[wv][s] = sum; }
        }
    }
    __syncthreads();

    // ---- phase 3: o[s][d] partials (bf16 out) ----
    {
        const float* vbase = cacheV + ((size_t)h * MCACHE + c0) * DHEAD + doff;
        float a[4][8];
#pragma unroll
        for (int j = 0; j < 4; ++j)
#pragma unroll
            for (int k = 0; k < 8; ++k) a[j][k] = 0.f;

        for (int m = 0; m < CHUNK_W; ++m) {
            const float4 p4 = *(const float4*)&sct[wv][m][sq * 4];
            const float4 v0 = *(const float4*)(vbase + (size_t)m * DHEAD);
            const float4 v1 = *(const float4*)(vbase + (size_t)m * DHEAD + 4);
            const float pj[4] = {p4.x, p4.y, p4.z, p4.w};
#pragma unroll
            for (int j = 0; j < 4; ++j) {
                a[j][0] += pj[j] * v0.x; a[j][1] += pj[j] * v0.y;
                a[j][2] += pj[j] * v0.z; a[j][3] += pj[j] * v0.w;
                a[j][4] += pj[j] * v1.x; a[j][5] += pj[j] * v1.y;
                a[j][6] += pj[j] * v1.z; a[j][7] += pj[j] * v1.w;
            }
        }

        if (overlap) {
            for (int gm = lo; gm < hi_; ++gm) {
                const float4 p4 = *(const float4*)&sct[wv][gm - c0][sq * 4];
                const float* vn = vb + (size_t)(gm - P) * NMODEL + h * DHEAD + doff;
                const float* vo = cacheV + ((size_t)h * MCACHE + gm) * DHEAD + doff;
                const float4 n0 = *(const float4*)(vn);
                const float4 n1 = *(const float4*)(vn + 4);
                const float4 o0 = *(const float4*)(vo);
                const float4 o1 = *(const float4*)(vo + 4);
                const float pj[4] = {p4.x, p4.y, p4.z, p4.w};
#pragma unroll
                for (int j = 0; j < 4; ++j) {
                    a[j][0] += pj[j] * (n0.x - o0.x); a[j][1] += pj[j] * (n0.y - o0.y);
                    a[j][2] += pj[j] * (n0.z - o0.z); a[j][3] += pj[j] * (n0.w - o0.w);
                    a[j][4] += pj[j] * (n1.x - o1.x); a[j][5] += pj[j] * (n1.y - o1.y);
                    a[j][6] += pj[j] * (n1.z - o1.z); a[j][7] += pj[j] * (n1.w - o1.w);
                }
            }
        }

        const size_t ob = (((size_t)h * NCHT + c) * S_LEN) * DHEAD;
#pragma unroll
        for (int j = 0; j < 4; ++j) {
            const int s = sq * 4 + j;
            uint4 pk;
            unsigned short* us = (unsigned short*)&pk;
#pragma unroll
            for (int k = 0; k < 8; ++k) us[k] = f2bf(a[j][k]);
            *(uint4*)&opart[ob + (size_t)s * DHEAD + doff] = pk;
        }
    }

    if (tid < 32) {
        const int w2 = tid >> 4, s = tid & 15;
        const int cc = bx * 2 + w2;
        mstat[((size_t)h * S_LEN + s) * NCHT + cc] = ml[w2][s];   // [h][s][c] layout
        lstat[((size_t)h * S_LEN + s) * NCHT + cc] = ll[w2][s];
    }
}

// ---------------- Kernel 4: combine chunk partials ----------------
// grid (S_LEN, HHEADS), block 512: cg = tid>>7 covers chunks cg, cg+4, ...
__global__ __launch_bounds__(512) void attn_combine(const unsigned short* __restrict__ opart,
                                                    const float* __restrict__ mstat,
                                                    const float* __restrict__ lstat,
                                                    float* __restrict__ out) {
    const int tid = threadIdx.x;
    const int cg  = tid >> 7;
    const int d   = tid & 127;
    const int s   = blockIdx.x;
    const int h   = blockIdx.y;

    __shared__ float mlds[NCHT], llds[NCHT], wlds[NCHT];
    __shared__ float olds[4][DHEAD];
    __shared__ float Llds[4];

    const size_t sb = ((size_t)h * S_LEN + s) * NCHT;
    if (tid < NCHT) { mlds[tid] = mstat[sb + tid]; llds[tid] = lstat[sb + tid]; }
    __syncthreads();

    // per-wave butterfly max over the 256 chunk maxima
    float gmax = fmaxf(fmaxf(mlds[tid & 63], mlds[(tid & 63) + 64]),
                       fmaxf(mlds[(tid & 63) + 128], mlds[(tid & 63) + 192]));
    for (int off = 32; off > 0; off >>= 1) gmax = fmaxf(gmax, __shfl_xor(gmax, off, 64));

    if (tid < NCHT) wlds[tid] = __expf(mlds[tid] - gmax);
    __syncthreads();

    float o = 0.f, L = 0.f;
    for (int c = cg; c < NCHT; c += 4) {
        const float w = wlds[c];
        o += w * bf2f(opart[(((size_t)h * NCHT + c) * S_LEN + s) * DHEAD + d]);
        L += w * llds[c];
    }
    olds[cg][d] = o;
    if (d == 0) Llds[cg] = L;
    __syncthreads();

    if (tid < DHEAD) {
        const float ot = olds[0][tid] + olds[1][tid] + olds[2][tid] + olds[3][tid];
        const float Lt = Llds[0] + Llds[1] + Llds[2] + Llds[3];
        out[((size_t)h * S_LEN + s) * DHEAD + tid] = ot / Lt;
    }
}

extern "C" void kernel_launch(void* const* d_in, const int* in_sizes, int n_in,
                              void* d_out, int out_size, void* d_ws, size_t ws_size,
                              hipStream_t stream) {
    const float* X      = (const float*)d_in[0];
    const float* Wq     = (const float*)d_in[1];
    const float* Wk     = (const float*)d_in[2];
    const float* Wv     = (const float*)d_in[3];
    const float* cacheK = (const float*)d_in[4];
    const float* cacheV = (const float*)d_in[5];
    const int*   P      = (const int*)d_in[6];
    float* out = (float*)d_out;
    float* ws  = (float*)d_ws;

    // ws (floats): qkv | region (part fp32 ALIASED with opart bf16) | mstat | lstat
    // region = max(6.29M, 8.39M) = 8.39M floats; total ~8.85M floats = 35.4 MB.
    float*          qkv   = ws;                                  // 196608
    float*          part  = qkv + 3 * S_LEN * NMODEL;
    unsigned short* opart = (unsigned short*)part;
    float*          mstat = part + REGION_ELEMS;
    float*          lstat = mstat + STAT_ELEMS;

    qkv_gemm<<<dim3(8, SPLITK, 3), 256, 0, stream>>>(X, Wq, Wk, Wv, part);
    qkv_reduce<<<(3 * S_LEN * NMODEL / 4) / 256, 256, 0, stream>>>(part, qkv);
    attn_partial<<<dim3(NCHT / 2, HHEADS), 128, 0, stream>>>(qkv, cacheK, cacheV, P,
                                                             opart, mstat, lstat);
    attn_combine<<<dim3(S_LEN, HHEADS), 512, 0, stream>>>(opart, mstat, lstat, out);
}